// Round 6
// baseline (865.603 us; speedup 1.0000x reference)
//
#include <hip/hip_runtime.h>
#include <hip/hip_bf16.h>

// GCN x3 + FC on a fixed random graph.
//   1. Bucket-partition edge build: LDS histogram -> scan -> LDS counting-sort
//      into bucket-contiguous PACKED edges (src | dst_local<<18). No CSR.
//   2. Per layer: EDGE-CENTRIC aggregation, one bucket (1024 dst) per block,
//      LDS accumulators (stride F+1), ds_add_f32, prescaled features
//      y = dinv*h -> out[v] = dinv[v]*(sum y[s] + y[v]).
//   3. Dense transforms apply dinv in epilogue; last transform fused with FC.
// R6: pull-CSR agg was latency-serialized (avg deg 8 -> dependent off/adj
// chain, degree-divergence). Edge-centric gives uniform full-lane gathers,
// ~128 lines in flight/CU, and deletes the adj scatter + off arrays.

#define NB   256     // dst buckets
#define NPB  1024    // nodes per bucket (N = 262144 = NB * NPB)
#define TILE 4096    // edges per partition tile
#define SRCMASK 0x3FFFF  // 18 bits

// ---- P1: global bucket histogram -------------------------------------------
__global__ void hist_kernel(const int* __restrict__ dst, int* __restrict__ ghist,
                            int E, int shift) {
    __shared__ int h[NB];
    int tid = threadIdx.x;
    h[tid] = 0;
    __syncthreads();
    int base = blockIdx.x * TILE;
    int cnt = min(TILE, E - base);
    for (int i = tid; i < cnt; i += 256)
        atomicAdd(&h[dst[base + i] >> shift], 1);
    __syncthreads();
    int v = h[tid];
    if (v) atomicAdd(&ghist[tid], v);
}

// ---- P2: scan bucket counts -> bbase[NB+1], init gcursor -------------------
__global__ void bscan_kernel(const int* __restrict__ ghist, int* __restrict__ bbase,
                             int* __restrict__ gcursor) {
    __shared__ int sh[NB];
    int tid = threadIdx.x;
    int v = ghist[tid];
    sh[tid] = v;
    __syncthreads();
    for (int o = 1; o < NB; o <<= 1) {
        int t = (tid >= o) ? sh[tid - o] : 0;
        __syncthreads();
        sh[tid] += t;
        __syncthreads();
    }
    int incl = sh[tid];
    bbase[tid] = incl - v;
    gcursor[tid] = incl - v;
    if (tid == NB - 1) bbase[NB] = incl;
}

// ---- P3: partition edges into bucket-contiguous packed stream --------------
__global__ void __launch_bounds__(256)
partition_kernel(const int* __restrict__ src, const int* __restrict__ dst,
                 int* __restrict__ gcursor, unsigned int* __restrict__ bedge,
                 int E, int shift, int mask) {
    __shared__ int h[NB], st[NB], gp[NB];
    __shared__ unsigned short rk[TILE];
    __shared__ int sd[TILE];
    __shared__ int ss[TILE];
    int tid = threadIdx.x;
    h[tid] = 0;
    __syncthreads();
    int base = blockIdx.x * TILE;
    int cnt = min(TILE, E - base);
    for (int i = tid; i < cnt; i += 256)
        rk[i] = (unsigned short)atomicAdd(&h[dst[base + i] >> shift], 1);
    __syncthreads();
    int hv = h[tid];
    st[tid] = hv;
    __syncthreads();
    for (int o = 1; o < NB; o <<= 1) {
        int t = (tid >= o) ? st[tid - o] : 0;
        __syncthreads();
        st[tid] += t;
        __syncthreads();
    }
    st[tid] -= hv;
    gp[tid] = hv ? atomicAdd(&gcursor[tid], hv) : 0;
    __syncthreads();
    for (int i = tid; i < cnt; i += 256) {
        int d = dst[base + i];
        int b = d >> shift;
        int pos = st[b] + rk[i];
        sd[pos] = d;
        ss[pos] = src[base + i];
    }
    __syncthreads();
    for (int i = tid; i < cnt; i += 256) {
        int d = sd[i];
        int b = d >> shift;
        int g = gp[b] + (i - st[b]);
        bedge[g] = (unsigned int)ss[i] | ((unsigned int)(d & mask) << 18);
    }
}

// ---- P4: per-bucket degree -> dinv; fused prescale y0 = dinv * x -----------
__global__ void __launch_bounds__(512)
degps_kernel(const unsigned int* __restrict__ bedge, const int* __restrict__ bbase,
             const float* __restrict__ x, float* __restrict__ dinv,
             float* __restrict__ y0) {
    __shared__ int deg[NPB];
    const int tid = threadIdx.x, b = blockIdx.x, vg0 = b * NPB;
    for (int i = tid; i < NPB; i += 512) deg[i] = 0;
    __syncthreads();
    const int s = bbase[b], e = bbase[b + 1];
    for (int i = s + tid; i < e; i += 512) atomicAdd(&deg[bedge[i] >> 18], 1);
    __syncthreads();
    for (int i = tid; i < NPB; i += 512) dinv[vg0 + i] = rsqrtf((float)(deg[i] + 1));
    for (int i = tid; i < NPB * 2; i += 512) {
        int v = i >> 1;
        float dv = rsqrtf((float)(deg[v] + 1));
        float4 t = ((const float4*)x)[(size_t)vg0 * 2 + i];
        t.x *= dv; t.y *= dv; t.z *= dv; t.w *= dv;
        ((float4*)y0)[(size_t)vg0 * 2 + i] = t;
    }
}

// ---- Edge-centric aggregation, one bucket per block ------------------------
// out[v] = dinv[v] * (sum y[s] + y[v]); C = float4-chunks per row.
// LDS acc stride C*4+1 floats: randomized banks for the dl-indexed atomics.
template <int C>
__global__ void __launch_bounds__(512, 1)
agg_lds_kernel(const float* __restrict__ y, const unsigned int* __restrict__ bedge,
               const int* __restrict__ bbase, const float* __restrict__ dinv,
               float* __restrict__ out) {
    constexpr int SW = C * 4 + 1;
    __shared__ float acc[NPB * SW];
    const int tid = threadIdx.x;
    const int b = blockIdx.x;
    const int vg0 = b * NPB;
    const float4* y4 = (const float4*)y;
    // self-term init: acc[v] = y[vg0+v]
    for (int i = tid; i < NPB * C; i += 512) {
        int v = i / C, q = i % C;
        float4 t = y4[(size_t)(vg0 + v) * C + q];
        float* a = &acc[v * SW + q * 4];
        a[0] = t.x; a[1] = t.y; a[2] = t.z; a[3] = t.w;
    }
    __syncthreads();
    const int s = bbase[b], e = bbase[b + 1];
    const int c = tid % C;
    const int stride = 512 / C;
    int i = s + tid / C;
    for (; i + stride < e; i += 2 * stride) {
        unsigned int p0 = bedge[i];
        unsigned int p1 = bedge[i + stride];
        float4 v0 = y4[(size_t)(p0 & SRCMASK) * C + c];
        float4 v1 = y4[(size_t)(p1 & SRCMASK) * C + c];
        float* a0 = &acc[(int)(p0 >> 18) * SW + c * 4];
        atomicAdd(a0 + 0, v0.x); atomicAdd(a0 + 1, v0.y);
        atomicAdd(a0 + 2, v0.z); atomicAdd(a0 + 3, v0.w);
        float* a1 = &acc[(int)(p1 >> 18) * SW + c * 4];
        atomicAdd(a1 + 0, v1.x); atomicAdd(a1 + 1, v1.y);
        atomicAdd(a1 + 2, v1.z); atomicAdd(a1 + 3, v1.w);
    }
    if (i < e) {
        unsigned int p0 = bedge[i];
        float4 v0 = y4[(size_t)(p0 & SRCMASK) * C + c];
        float* a0 = &acc[(int)(p0 >> 18) * SW + c * 4];
        atomicAdd(a0 + 0, v0.x); atomicAdd(a0 + 1, v0.y);
        atomicAdd(a0 + 2, v0.z); atomicAdd(a0 + 3, v0.w);
    }
    __syncthreads();
    // epilogue: out[v] = dinv[v] * acc[v], coalesced
    for (int j = tid; j < NPB * C; j += 512) {
        int v = j / C, q = j % C;
        float dv = dinv[vg0 + v];
        const float* a = &acc[v * SW + q * 4];
        float4 t;
        t.x = a[0] * dv; t.y = a[1] * dv; t.z = a[2] * dv; t.w = a[3] * dv;
        ((float4*)out)[(size_t)(vg0 + v) * C + q] = t;
    }
}

// ---- Dense per-node transform, epilogue pre-scales by dinv -----------------
// out[v] = dinv[v] * relu(in[v] @ W + b)
template <int FIN, int FOUT>
__global__ void transform_kernel(const float* __restrict__ in, const float* __restrict__ W,
                                 const float* __restrict__ b, const float* __restrict__ dinv,
                                 float* __restrict__ out, int n) {
    __shared__ float Ws[FIN * FOUT];
    __shared__ float bs[FOUT];
    for (int i = threadIdx.x; i < FIN * FOUT; i += blockDim.x) Ws[i] = W[i];
    if (threadIdx.x < FOUT) bs[threadIdx.x] = b[threadIdx.x];
    __syncthreads();
    int v = blockIdx.x * blockDim.x + threadIdx.x;
    if (v >= n) return;
    float a[FIN];
    const float4* in4 = (const float4*)(in + (size_t)v * FIN);
#pragma unroll
    for (int k = 0; k < FIN / 4; k++) {
        float4 t = in4[k];
        a[4 * k] = t.x; a[4 * k + 1] = t.y; a[4 * k + 2] = t.z; a[4 * k + 3] = t.w;
    }
    float dv = dinv[v];
    float4* out4 = (float4*)(out + (size_t)v * FOUT);
#pragma unroll
    for (int j = 0; j < FOUT; j += 4) {
        float acc0 = bs[j], acc1 = bs[j + 1], acc2 = bs[j + 2], acc3 = bs[j + 3];
#pragma unroll
        for (int k = 0; k < FIN; k++) {
            float xv = a[k];
            acc0 += xv * Ws[k * FOUT + j];
            acc1 += xv * Ws[k * FOUT + j + 1];
            acc2 += xv * Ws[k * FOUT + j + 2];
            acc3 += xv * Ws[k * FOUT + j + 3];
        }
        float4 o;
        o.x = dv * fmaxf(acc0, 0.f); o.y = dv * fmaxf(acc1, 0.f);
        o.z = dv * fmaxf(acc2, 0.f); o.w = dv * fmaxf(acc3, 0.f);
        out4[j / 4] = o;
    }
}

// ---- Fused layer-3 transform + FC (block-cooperative) ----------------------
#define T3_NODES 32
__global__ void __launch_bounds__(256)
t3fc_kernel(const float* __restrict__ in,
            const float* __restrict__ W3, const float* __restrict__ b3,
            const float* __restrict__ Wf, const float* __restrict__ bf,
            float* __restrict__ out, int n) {
    __shared__ float W3s[32 * 64];
    __shared__ float Wfs[64 * 64];
    __shared__ float b3s[64], bfs[64];
    __shared__ float ins[T3_NODES][33];
    __shared__ float tts[T3_NODES][65];
    const int tid = threadIdx.x;
    for (int i = tid; i < 32 * 64; i += 256) W3s[i] = W3[i];
    for (int i = tid; i < 64 * 64; i += 256) Wfs[i] = Wf[i];
    if (tid < 64) { b3s[tid] = b3[tid]; bfs[tid] = bf[tid]; }
    const int vbase = blockIdx.x * T3_NODES;
    {
        const float4* g = (const float4*)(in + (size_t)vbase * 32);
        float4 t = g[tid];
        int v = tid >> 3, c = (tid & 7) * 4;
        ins[v][c] = t.x; ins[v][c + 1] = t.y; ins[v][c + 2] = t.z; ins[v][c + 3] = t.w;
    }
    __syncthreads();
    const int tx = tid & 15;
    const int ty = tid >> 4;
    const int j0 = tx * 4;
    {
        float a00 = b3s[j0], a01 = b3s[j0 + 1], a02 = b3s[j0 + 2], a03 = b3s[j0 + 3];
        float a10 = a00, a11 = a01, a12 = a02, a13 = a03;
#pragma unroll
        for (int k = 0; k < 32; k++) {
            float4 w = *(const float4*)&W3s[k * 64 + j0];
            float x0 = ins[ty][k];
            float x1 = ins[ty + 16][k];
            a00 += x0 * w.x; a01 += x0 * w.y; a02 += x0 * w.z; a03 += x0 * w.w;
            a10 += x1 * w.x; a11 += x1 * w.y; a12 += x1 * w.z; a13 += x1 * w.w;
        }
        tts[ty][j0]          = fmaxf(a00, 0.f); tts[ty][j0 + 1]      = fmaxf(a01, 0.f);
        tts[ty][j0 + 2]      = fmaxf(a02, 0.f); tts[ty][j0 + 3]      = fmaxf(a03, 0.f);
        tts[ty + 16][j0]     = fmaxf(a10, 0.f); tts[ty + 16][j0 + 1] = fmaxf(a11, 0.f);
        tts[ty + 16][j0 + 2] = fmaxf(a12, 0.f); tts[ty + 16][j0 + 3] = fmaxf(a13, 0.f);
    }
    __syncthreads();
    {
        float a00 = bfs[j0], a01 = bfs[j0 + 1], a02 = bfs[j0 + 2], a03 = bfs[j0 + 3];
        float a10 = a00, a11 = a01, a12 = a02, a13 = a03;
#pragma unroll
        for (int k = 0; k < 64; k++) {
            float4 w = *(const float4*)&Wfs[k * 64 + j0];
            float x0 = tts[ty][k];
            float x1 = tts[ty + 16][k];
            a00 += x0 * w.x; a01 += x0 * w.y; a02 += x0 * w.z; a03 += x0 * w.w;
            a10 += x1 * w.x; a11 += x1 * w.y; a12 += x1 * w.z; a13 += x1 * w.w;
        }
        float4 o0; o0.x = a00; o0.y = a01; o0.z = a02; o0.w = a03;
        float4 o1; o1.x = a10; o1.y = a11; o1.z = a12; o1.w = a13;
        *(float4*)(out + ((size_t)(vbase + ty)) * 64 + j0) = o0;
        *(float4*)(out + ((size_t)(vbase + ty + 16)) * 64 + j0) = o1;
    }
}

extern "C" void kernel_launch(void* const* d_in, const int* in_sizes, int n_in,
                              void* d_out, int out_size, void* d_ws, size_t ws_size,
                              hipStream_t stream) {
    const float* x  = (const float*)d_in[0];
    const float* W1 = (const float*)d_in[1];
    const float* b1 = (const float*)d_in[2];
    const float* W2 = (const float*)d_in[3];
    const float* b2 = (const float*)d_in[4];
    const float* W3 = (const float*)d_in[5];
    const float* b3 = (const float*)d_in[6];
    const float* Wf = (const float*)d_in[7];
    const float* bf = (const float*)d_in[8];
    const int*   ei = (const int*)d_in[9];

    const int N = in_sizes[0] / 8;   // 262144
    const int E = in_sizes[9] / 2;   // 2097152
    const int* srcv = ei;
    const int* dstv = ei + E;
    const int shift = 10;            // log2(NPB)

    // Workspace layout
    char* p = (char*)d_ws;
    unsigned int* bedge = (unsigned int*)p;  p += (size_t)E * 4;
    float* dinv   = (float*)p;               p += (size_t)N * 4;
    int*   ghist  = (int*)p;                 p += NB * 4;
    int*   bbase  = (int*)p;                 p += (NB + 1) * 4;
    int*   gcur   = (int*)p;                 p += NB * 4 + 4;
    float* bufA   = (float*)p;               p += (size_t)N * 32 * 4;
    float* bufB   = (float*)p;               p += (size_t)N * 32 * 4;
    // y0 lives in bufA's upper half (dead once agg<4> overwrites bufA[0,N*16))
    float* y0 = bufA + (size_t)N * 8;

    hipMemsetAsync(ghist, 0, NB * 4, stream);

    int nt = (E + TILE - 1) / TILE;  // 512 tiles
    hist_kernel<<<nt, 256, 0, stream>>>(dstv, ghist, E, shift);
    bscan_kernel<<<1, NB, 0, stream>>>(ghist, bbase, gcur);
    partition_kernel<<<nt, 256, 0, stream>>>(srcv, dstv, gcur, bedge, E, shift, NPB - 1);
    degps_kernel<<<NB, 512, 0, stream>>>(bedge, bbase, x, dinv, y0);

    // Layer 1: aggregate y0 [N,8] -> a1 = bufA[0,N*8), transform 8->16 -> y1 = bufB
    agg_lds_kernel<2><<<NB, 512, 0, stream>>>(y0, bedge, bbase, dinv, bufA);
    transform_kernel<8, 16><<<(N + 255) / 256, 256, 0, stream>>>(bufA, W1, b1, dinv, bufB, N);

    // Layer 2: aggregate y1 [N,16] -> a2 = bufA, transform 16->32 -> y2 = bufB
    agg_lds_kernel<4><<<NB, 512, 0, stream>>>(bufB, bedge, bbase, dinv, bufA);
    transform_kernel<16, 32><<<(N + 255) / 256, 256, 0, stream>>>(bufA, W2, b2, dinv, bufB, N);

    // Layer 3: aggregate y2 [N,32] -> a3 = bufA, fused transform+FC -> out
    agg_lds_kernel<8><<<NB, 512, 0, stream>>>(bufB, bedge, bbase, dinv, bufA);
    t3fc_kernel<<<(N / T3_NODES), 256, 0, stream>>>(bufA, W3, b3, Wf, bf, (float*)d_out, N);
}

// Round 7
// 343.875 us; speedup vs baseline: 2.5172x; 2.5172x over previous
//
#include <hip/hip_runtime.h>
#include <hip/hip_bf16.h>

// GCN x3 + FC on a fixed random graph.  (R7: revert to R5 pull-CSR; R6's
// edge-centric LDS agg died on occupancy: 132KB LDS -> 1 block/CU -> 0.8TB/s.)
//   1. Bucket-partition CSR build: hist -> scan -> packed partition
//      (src|dl<<18) -> per-bucket build (LDS atomics, coalesced I/O) with
//      fused prescale y0 = dinv*x.
//   2. Pull aggregation over pre-scaled features y = dinv*h:
//      out[v] = dinv[v]*(sum y[s] + y[v]).  Transform fused into agg epilogue
//      via per-block LDS staging (aggt1: 8->16, aggt2: 16->32).
//   3. y2 stored bf16 (64B rows): halves agg3's random-gather sectors
//      (R5 profile implies 64B fetch granularity: agg<2>/agg<4> cheaper than
//      agg<8> despite equal edge count).
//   4. t3fc: fused transform3+FC, block-cooperative (R2).

#define NB   256     // dst buckets
#define NPB  1024    // nodes per bucket (N = NB*NPB)
#define TILE 4096    // edges per partition tile
#define SRCMASK 0x3FFFFu

__device__ __forceinline__ float bf_lo(unsigned u) { return __uint_as_float(u << 16); }
__device__ __forceinline__ float bf_hi(unsigned u) { return __uint_as_float(u & 0xFFFF0000u); }
__device__ __forceinline__ unsigned bf_rne(float f) {   // fp32 -> bf16 bits (RNE)
    unsigned b = __float_as_uint(f);
    return (b + 0x7FFFu + ((b >> 16) & 1u)) >> 16;
}

// ---- P1: global bucket histogram -------------------------------------------
__global__ void hist_kernel(const int* __restrict__ dst, int* __restrict__ ghist,
                            int E, int shift) {
    __shared__ int h[NB];
    int tid = threadIdx.x;
    h[tid] = 0;
    __syncthreads();
    int base = blockIdx.x * TILE;
    int cnt = min(TILE, E - base);
    for (int i = tid; i < cnt; i += 256)
        atomicAdd(&h[dst[base + i] >> shift], 1);
    __syncthreads();
    int v = h[tid];
    if (v) atomicAdd(&ghist[tid], v);
}

// ---- P2: scan bucket counts -> bbase[NB+1], init gcursor -------------------
__global__ void bscan_kernel(const int* __restrict__ ghist, int* __restrict__ bbase,
                             int* __restrict__ gcursor) {
    __shared__ int sh[NB];
    int tid = threadIdx.x;
    int v = ghist[tid];
    sh[tid] = v;
    __syncthreads();
    for (int o = 1; o < NB; o <<= 1) {
        int t = (tid >= o) ? sh[tid - o] : 0;
        __syncthreads();
        sh[tid] += t;
        __syncthreads();
    }
    int incl = sh[tid];
    bbase[tid] = incl - v;
    gcursor[tid] = incl - v;
    if (tid == NB - 1) bbase[NB] = incl;
}

// ---- P3: partition edges into bucket-contiguous packed stream --------------
__global__ void __launch_bounds__(256)
partition_kernel(const int* __restrict__ src, const int* __restrict__ dst,
                 int* __restrict__ gcursor, unsigned int* __restrict__ bedge,
                 int E, int shift, int mask) {
    __shared__ int h[NB], st[NB], gp[NB];
    __shared__ unsigned short rk[TILE];
    __shared__ int sd[TILE];
    __shared__ int ss[TILE];
    int tid = threadIdx.x;
    h[tid] = 0;
    __syncthreads();
    int base = blockIdx.x * TILE;
    int cnt = min(TILE, E - base);
    for (int i = tid; i < cnt; i += 256)
        rk[i] = (unsigned short)atomicAdd(&h[dst[base + i] >> shift], 1);
    __syncthreads();
    int hv = h[tid];
    st[tid] = hv;
    __syncthreads();
    for (int o = 1; o < NB; o <<= 1) {
        int t = (tid >= o) ? st[tid - o] : 0;
        __syncthreads();
        st[tid] += t;
        __syncthreads();
    }
    st[tid] -= hv;
    gp[tid] = hv ? atomicAdd(&gcursor[tid], hv) : 0;
    __syncthreads();
    for (int i = tid; i < cnt; i += 256) {
        int d = dst[base + i];
        int b = d >> shift;
        int pos = st[b] + rk[i];
        sd[pos] = d;
        ss[pos] = src[base + i];
    }
    __syncthreads();
    for (int i = tid; i < cnt; i += 256) {
        int d = sd[i];
        int b = d >> shift;
        int g = gp[b] + (i - st[b]);
        bedge[g] = (unsigned int)ss[i] | ((unsigned int)(d & mask) << 18);
    }
}

// ---- P4: per-bucket CSR build + fused prescale -----------------------------
__global__ void __launch_bounds__(256)
build_kernel(const int* __restrict__ bbase, const unsigned int* __restrict__ bedge,
             const float* __restrict__ x,
             int* __restrict__ off, float* __restrict__ dinv, int* __restrict__ adj,
             float* __restrict__ y0) {
    __shared__ int deg1[NPB];
    __shared__ int cur[NPB];
    __shared__ int bs[256];
    int tid = threadIdx.x;
    int b = blockIdx.x;
    int s = bbase[b], e = bbase[b + 1];
    int base = tid * 4;
#pragma unroll
    for (int i = 0; i < 4; i++) deg1[base + i] = 0;
    __syncthreads();
    for (int i = s + tid; i < e; i += 256)
        atomicAdd(&deg1[bedge[i] >> 18], 1);
    __syncthreads();
    int d0 = deg1[base], d1 = deg1[base + 1], d2 = deg1[base + 2], d3 = deg1[base + 3];
    int th = d0 + d1 + d2 + d3;
    bs[tid] = th;
    __syncthreads();
    for (int o = 1; o < 256; o <<= 1) {
        int t = (tid >= o) ? bs[tid - o] : 0;
        __syncthreads();
        bs[tid] += t;
        __syncthreads();
    }
    int run = s + bs[tid] - th;
    int vb = b * NPB + base;
    off[vb]     = run; cur[base]     = run; dinv[vb]     = rsqrtf((float)(d0 + 1)); run += d0;
    off[vb + 1] = run; cur[base + 1] = run; dinv[vb + 1] = rsqrtf((float)(d1 + 1)); run += d1;
    off[vb + 2] = run; cur[base + 2] = run; dinv[vb + 2] = rsqrtf((float)(d2 + 1)); run += d2;
    off[vb + 3] = run; cur[base + 3] = run; dinv[vb + 3] = rsqrtf((float)(d3 + 1)); run += d3;
    if (b == NB - 1 && tid == 255) off[NB * NPB] = e;   // sentinel off[N] = E
    __syncthreads();
    for (int i = s + tid; i < e; i += 256) {
        unsigned int pk = bedge[i];
        int p = atomicAdd(&cur[pk >> 18], 1);
        adj[p] = (int)(pk & SRCMASK);
    }
    // fused prescale: y0[v] = dinv[v] * x[v]  (bucket rows, coalesced)
    for (int i = tid; i < NPB * 2; i += 256) {
        int v = i >> 1;
        float dv = rsqrtf((float)(deg1[v] + 1));
        float4 t = ((const float4*)x)[(size_t)b * NPB * 2 + i];
        t.x *= dv; t.y *= dv; t.z *= dv; t.w *= dv;
        ((float4*)y0)[(size_t)b * NPB * 2 + i] = t;
    }
}

// ---- Fused agg(8-dim) + transform 8->16 ------------------------------------
// gather: 2 lanes/node; epilogue: a1 = dinv*(sum+self) staged in LDS, then
// y1[v] = dinv[v]*relu(a1 @ W1 + b1).
__global__ void __launch_bounds__(256)
aggt1_kernel(const float* __restrict__ y0, const int* __restrict__ off,
             const int* __restrict__ adj, const float* __restrict__ dinv,
             const float* __restrict__ W1, const float* __restrict__ b1,
             float* __restrict__ y1) {
    __shared__ float Ws[8 * 16];
    __shared__ float bsh[16];
    __shared__ float sh[128][9];
    const int tid = threadIdx.x;
    if (tid < 128) Ws[tid] = W1[tid];
    if (tid < 16) bsh[tid] = b1[tid];
    const int vbase = blockIdx.x * 128;
    const int vl = tid >> 1, c = tid & 1;
    const int vg = vbase + vl;
    const float4* y4 = (const float4*)y0;
    int beg = off[vg];
    int end = off[vg + 1];
    float4 a0 = y4[(size_t)vg * 2 + c];   // self
    float4 a1, a2, a3;
    a1.x = a1.y = a1.z = a1.w = 0.f;
    a2.x = a2.y = a2.z = a2.w = 0.f;
    a3.x = a3.y = a3.z = a3.w = 0.f;
    int e = beg;
    for (; e + 4 <= end; e += 4) {
        int s0 = adj[e], s1 = adj[e + 1], s2 = adj[e + 2], s3 = adj[e + 3];
        float4 x0 = y4[(size_t)s0 * 2 + c];
        float4 x1 = y4[(size_t)s1 * 2 + c];
        float4 x2 = y4[(size_t)s2 * 2 + c];
        float4 x3 = y4[(size_t)s3 * 2 + c];
        a0.x += x0.x; a0.y += x0.y; a0.z += x0.z; a0.w += x0.w;
        a1.x += x1.x; a1.y += x1.y; a1.z += x1.z; a1.w += x1.w;
        a2.x += x2.x; a2.y += x2.y; a2.z += x2.z; a2.w += x2.w;
        a3.x += x3.x; a3.y += x3.y; a3.z += x3.z; a3.w += x3.w;
    }
    for (; e < end; e++) {
        float4 xs = y4[(size_t)adj[e] * 2 + c];
        a1.x += xs.x; a1.y += xs.y; a1.z += xs.z; a1.w += xs.w;
    }
    float dv = dinv[vg];
    sh[vl][c * 4 + 0] = ((a0.x + a1.x) + (a2.x + a3.x)) * dv;
    sh[vl][c * 4 + 1] = ((a0.y + a1.y) + (a2.y + a3.y)) * dv;
    sh[vl][c * 4 + 2] = ((a0.z + a1.z) + (a2.z + a3.z)) * dv;
    sh[vl][c * 4 + 3] = ((a0.w + a1.w) + (a2.w + a3.w)) * dv;
    __syncthreads();
    // transform: thread -> (node nl, half hf), 8 outputs
    const int nl = tid & 127, hf = tid >> 7, j0 = hf * 8;
    float in0 = sh[nl][0], in1 = sh[nl][1], in2 = sh[nl][2], in3 = sh[nl][3];
    float in4 = sh[nl][4], in5 = sh[nl][5], in6 = sh[nl][6], in7 = sh[nl][7];
    float dn = dinv[vbase + nl];
    float o[8];
#pragma unroll
    for (int jj = 0; jj < 8; jj++) {
        int j = j0 + jj;
        float acc = bsh[j];
        acc += in0 * Ws[0 * 16 + j]; acc += in1 * Ws[1 * 16 + j];
        acc += in2 * Ws[2 * 16 + j]; acc += in3 * Ws[3 * 16 + j];
        acc += in4 * Ws[4 * 16 + j]; acc += in5 * Ws[5 * 16 + j];
        acc += in6 * Ws[6 * 16 + j]; acc += in7 * Ws[7 * 16 + j];
        o[jj] = dn * fmaxf(acc, 0.f);
    }
    float4* out4 = (float4*)(y1 + (size_t)(vbase + nl) * 16 + j0);
    float4 t0; t0.x = o[0]; t0.y = o[1]; t0.z = o[2]; t0.w = o[3];
    float4 t1; t1.x = o[4]; t1.y = o[5]; t1.z = o[6]; t1.w = o[7];
    out4[0] = t0; out4[1] = t1;
}

// ---- Fused agg(16-dim) + transform 16->32, bf16 output ---------------------
__global__ void __launch_bounds__(256)
aggt2_kernel(const float* __restrict__ y1, const int* __restrict__ off,
             const int* __restrict__ adj, const float* __restrict__ dinv,
             const float* __restrict__ W2, const float* __restrict__ b2,
             unsigned int* __restrict__ y2b) {
    __shared__ float Ws[16 * 32];
    __shared__ float bsh[32];
    __shared__ float sh[64][17];
    const int tid = threadIdx.x;
    for (int i = tid; i < 16 * 32; i += 256) Ws[i] = W2[i];
    if (tid < 32) bsh[tid] = b2[tid];
    const int vbase = blockIdx.x * 64;
    const int vl = tid >> 2, c = tid & 3;
    const int vg = vbase + vl;
    const float4* y4 = (const float4*)y1;
    int beg = off[vg];
    int end = off[vg + 1];
    float4 a0 = y4[(size_t)vg * 4 + c];   // self
    float4 a1, a2, a3;
    a1.x = a1.y = a1.z = a1.w = 0.f;
    a2.x = a2.y = a2.z = a2.w = 0.f;
    a3.x = a3.y = a3.z = a3.w = 0.f;
    int e = beg;
    for (; e + 4 <= end; e += 4) {
        int s0 = adj[e], s1 = adj[e + 1], s2 = adj[e + 2], s3 = adj[e + 3];
        float4 x0 = y4[(size_t)s0 * 4 + c];
        float4 x1 = y4[(size_t)s1 * 4 + c];
        float4 x2 = y4[(size_t)s2 * 4 + c];
        float4 x3 = y4[(size_t)s3 * 4 + c];
        a0.x += x0.x; a0.y += x0.y; a0.z += x0.z; a0.w += x0.w;
        a1.x += x1.x; a1.y += x1.y; a1.z += x1.z; a1.w += x1.w;
        a2.x += x2.x; a2.y += x2.y; a2.z += x2.z; a2.w += x2.w;
        a3.x += x3.x; a3.y += x3.y; a3.z += x3.z; a3.w += x3.w;
    }
    for (; e < end; e++) {
        float4 xs = y4[(size_t)adj[e] * 4 + c];
        a1.x += xs.x; a1.y += xs.y; a1.z += xs.z; a1.w += xs.w;
    }
    float dv = dinv[vg];
    sh[vl][c * 4 + 0] = ((a0.x + a1.x) + (a2.x + a3.x)) * dv;
    sh[vl][c * 4 + 1] = ((a0.y + a1.y) + (a2.y + a3.y)) * dv;
    sh[vl][c * 4 + 2] = ((a0.z + a1.z) + (a2.z + a3.z)) * dv;
    sh[vl][c * 4 + 3] = ((a0.w + a1.w) + (a2.w + a3.w)) * dv;
    __syncthreads();
    // transform: thread -> (node nl, quarter q), 8 outputs, pack bf16
    const int nl = tid & 63, q = tid >> 6, j0 = q * 8;
    float in[16];
#pragma unroll
    for (int k = 0; k < 16; k++) in[k] = sh[nl][k];
    float dn = dinv[vbase + nl];
    unsigned r[8];
#pragma unroll
    for (int jj = 0; jj < 8; jj++) {
        int j = j0 + jj;
        float acc = bsh[j];
#pragma unroll
        for (int k = 0; k < 16; k++) acc += in[k] * Ws[k * 32 + j];
        r[jj] = bf_rne(dn * fmaxf(acc, 0.f));
    }
    uint4 pk;
    pk.x = r[0] | (r[1] << 16); pk.y = r[2] | (r[3] << 16);
    pk.z = r[4] | (r[5] << 16); pk.w = r[6] | (r[7] << 16);
    ((uint4*)y2b)[(size_t)(vbase + nl) * 4 + q] = pk;
}

// ---- agg(32-dim, bf16 rows) -> fp32 a3 -------------------------------------
// 4 lanes/node, each lane one uint4 (8 bf16) chunk; 2-way unrolled.
__global__ void __launch_bounds__(256)
agg_bf16_kernel(const unsigned int* __restrict__ y2b, const int* __restrict__ off,
                const int* __restrict__ adj, const float* __restrict__ dinv,
                float* __restrict__ a3out, int n) {
    int t = blockIdx.x * 256 + threadIdx.x;
    int v = t >> 2, c = t & 3;
    if (v >= n) return;
    const uint4* yb = (const uint4*)y2b;
    uint4 us = yb[(size_t)v * 4 + c];   // self
    float p0 = bf_lo(us.x), p1 = bf_hi(us.x), p2 = bf_lo(us.y), p3 = bf_hi(us.y);
    float p4 = bf_lo(us.z), p5 = bf_hi(us.z), p6 = bf_lo(us.w), p7 = bf_hi(us.w);
    float q0 = 0, q1 = 0, q2 = 0, q3 = 0, q4 = 0, q5 = 0, q6 = 0, q7 = 0;
    int beg = off[v], end = off[v + 1];
    int e = beg;
    for (; e + 2 <= end; e += 2) {
        int s0 = adj[e], s1 = adj[e + 1];
        uint4 u0 = yb[(size_t)s0 * 4 + c];
        uint4 u1 = yb[(size_t)s1 * 4 + c];
        p0 += bf_lo(u0.x); p1 += bf_hi(u0.x); p2 += bf_lo(u0.y); p3 += bf_hi(u0.y);
        p4 += bf_lo(u0.z); p5 += bf_hi(u0.z); p6 += bf_lo(u0.w); p7 += bf_hi(u0.w);
        q0 += bf_lo(u1.x); q1 += bf_hi(u1.x); q2 += bf_lo(u1.y); q3 += bf_hi(u1.y);
        q4 += bf_lo(u1.z); q5 += bf_hi(u1.z); q6 += bf_lo(u1.w); q7 += bf_hi(u1.w);
    }
    if (e < end) {
        uint4 u0 = yb[(size_t)adj[e] * 4 + c];
        p0 += bf_lo(u0.x); p1 += bf_hi(u0.x); p2 += bf_lo(u0.y); p3 += bf_hi(u0.y);
        p4 += bf_lo(u0.z); p5 += bf_hi(u0.z); p6 += bf_lo(u0.w); p7 += bf_hi(u0.w);
    }
    float dv = dinv[v];
    float4 o0, o1;
    o0.x = (p0 + q0) * dv; o0.y = (p1 + q1) * dv; o0.z = (p2 + q2) * dv; o0.w = (p3 + q3) * dv;
    o1.x = (p4 + q4) * dv; o1.y = (p5 + q5) * dv; o1.z = (p6 + q6) * dv; o1.w = (p7 + q7) * dv;
    float4* out4 = (float4*)a3out;
    out4[(size_t)v * 8 + c * 2]     = o0;
    out4[(size_t)v * 8 + c * 2 + 1] = o1;
}

// ---- Fused layer-3 transform + FC (block-cooperative) ----------------------
#define T3_NODES 32
__global__ void __launch_bounds__(256)
t3fc_kernel(const float* __restrict__ in,
            const float* __restrict__ W3, const float* __restrict__ b3,
            const float* __restrict__ Wf, const float* __restrict__ bf,
            float* __restrict__ out, int n) {
    __shared__ float W3s[32 * 64];
    __shared__ float Wfs[64 * 64];
    __shared__ float b3s[64], bfs[64];
    __shared__ float ins[T3_NODES][33];
    __shared__ float tts[T3_NODES][65];
    const int tid = threadIdx.x;
    for (int i = tid; i < 32 * 64; i += 256) W3s[i] = W3[i];
    for (int i = tid; i < 64 * 64; i += 256) Wfs[i] = Wf[i];
    if (tid < 64) { b3s[tid] = b3[tid]; bfs[tid] = bf[tid]; }
    const int vbase = blockIdx.x * T3_NODES;
    {
        const float4* g = (const float4*)(in + (size_t)vbase * 32);
        float4 t = g[tid];
        int v = tid >> 3, c = (tid & 7) * 4;
        ins[v][c] = t.x; ins[v][c + 1] = t.y; ins[v][c + 2] = t.z; ins[v][c + 3] = t.w;
    }
    __syncthreads();
    const int tx = tid & 15;
    const int ty = tid >> 4;
    const int j0 = tx * 4;
    {
        float a00 = b3s[j0], a01 = b3s[j0 + 1], a02 = b3s[j0 + 2], a03 = b3s[j0 + 3];
        float a10 = a00, a11 = a01, a12 = a02, a13 = a03;
#pragma unroll
        for (int k = 0; k < 32; k++) {
            float4 w = *(const float4*)&W3s[k * 64 + j0];
            float x0 = ins[ty][k];
            float x1 = ins[ty + 16][k];
            a00 += x0 * w.x; a01 += x0 * w.y; a02 += x0 * w.z; a03 += x0 * w.w;
            a10 += x1 * w.x; a11 += x1 * w.y; a12 += x1 * w.z; a13 += x1 * w.w;
        }
        tts[ty][j0]          = fmaxf(a00, 0.f); tts[ty][j0 + 1]      = fmaxf(a01, 0.f);
        tts[ty][j0 + 2]      = fmaxf(a02, 0.f); tts[ty][j0 + 3]      = fmaxf(a03, 0.f);
        tts[ty + 16][j0]     = fmaxf(a10, 0.f); tts[ty + 16][j0 + 1] = fmaxf(a11, 0.f);
        tts[ty + 16][j0 + 2] = fmaxf(a12, 0.f); tts[ty + 16][j0 + 3] = fmaxf(a13, 0.f);
    }
    __syncthreads();
    {
        float a00 = bfs[j0], a01 = bfs[j0 + 1], a02 = bfs[j0 + 2], a03 = bfs[j0 + 3];
        float a10 = a00, a11 = a01, a12 = a02, a13 = a03;
#pragma unroll
        for (int k = 0; k < 64; k++) {
            float4 w = *(const float4*)&Wfs[k * 64 + j0];
            float x0 = tts[ty][k];
            float x1 = tts[ty + 16][k];
            a00 += x0 * w.x; a01 += x0 * w.y; a02 += x0 * w.z; a03 += x0 * w.w;
            a10 += x1 * w.x; a11 += x1 * w.y; a12 += x1 * w.z; a13 += x1 * w.w;
        }
        float4 o0; o0.x = a00; o0.y = a01; o0.z = a02; o0.w = a03;
        float4 o1; o1.x = a10; o1.y = a11; o1.z = a12; o1.w = a13;
        *(float4*)(out + ((size_t)(vbase + ty)) * 64 + j0) = o0;
        *(float4*)(out + ((size_t)(vbase + ty + 16)) * 64 + j0) = o1;
    }
}

extern "C" void kernel_launch(void* const* d_in, const int* in_sizes, int n_in,
                              void* d_out, int out_size, void* d_ws, size_t ws_size,
                              hipStream_t stream) {
    const float* x  = (const float*)d_in[0];
    const float* W1 = (const float*)d_in[1];
    const float* b1 = (const float*)d_in[2];
    const float* W2 = (const float*)d_in[3];
    const float* b2 = (const float*)d_in[4];
    const float* W3 = (const float*)d_in[5];
    const float* b3 = (const float*)d_in[6];
    const float* Wf = (const float*)d_in[7];
    const float* bf = (const float*)d_in[8];
    const int*   ei = (const int*)d_in[9];

    const int N = in_sizes[0] / 8;   // 262144
    const int E = in_sizes[9] / 2;   // 2097152
    const int* srcv = ei;
    const int* dstv = ei + E;
    const int shift = 10;            // log2(NPB)

    // Workspace layout (16B-aligned chunks)
    char* p = (char*)d_ws;
    auto take = [&p](size_t bytes) { char* q = p; p += (bytes + 63) & ~size_t(63); return q; };
    int*   off   = (int*)take((size_t)(N + 16) * 4);
    float* dinv  = (float*)take((size_t)N * 4);
    int*   adj   = (int*)take((size_t)E * 4);
    int*   ghist = (int*)take(NB * 4);
    int*   bbase = (int*)take((NB + 1) * 4);
    int*   gcur  = (int*)take(NB * 4);
    float* bufA  = (float*)take((size_t)N * 32 * 4);   // y0 [0,8MB) then a3 (33MB)
    float* y1    = (float*)take((size_t)N * 16 * 4);   // 16MB
    char*  regX  = take((size_t)N * 32 * 2);           // 16MB: bedge (8MB) then y2b
    unsigned int* bedge = (unsigned int*)regX;
    unsigned int* y2b   = (unsigned int*)regX;
    float* y0 = bufA;

    hipMemsetAsync(ghist, 0, NB * 4, stream);

    int nt = (E + TILE - 1) / TILE;  // 512 tiles
    hist_kernel<<<nt, 256, 0, stream>>>(dstv, ghist, E, shift);
    bscan_kernel<<<1, NB, 0, stream>>>(ghist, bbase, gcur);
    partition_kernel<<<nt, 256, 0, stream>>>(srcv, dstv, gcur, bedge, E, shift, NPB - 1);
    build_kernel<<<NB, 256, 0, stream>>>(bbase, bedge, x, off, dinv, adj, y0);

    // L1: agg(y0) + transform 8->16 -> y1
    aggt1_kernel<<<N / 128, 256, 0, stream>>>(y0, off, adj, dinv, W1, b1, y1);
    // L2: agg(y1) + transform 16->32 -> y2b (bf16; overwrites dead bedge)
    aggt2_kernel<<<N / 64, 256, 0, stream>>>(y1, off, adj, dinv, W2, b2, y2b);
    // L3: agg(y2b) -> a3 (bufA; y0 dead), then fused transform+FC -> out
    agg_bf16_kernel<<<(N * 4) / 256, 256, 0, stream>>>(y2b, off, adj, dinv, bufA, N);
    t3fc_kernel<<<N / T3_NODES, 256, 0, stream>>>(bufA, W3, b3, Wf, bf, (float*)d_out, N);
}